// Round 17
// baseline (1144.242 us; speedup 1.0000x reference)
//
#include <hip/hip_runtime.h>
#include <hip/hip_bf16.h>
#include <stdint.h>

typedef __attribute__((ext_vector_type(8))) short short8_t;   // 8 x bf16 (4 VGPRs)
typedef __attribute__((ext_vector_type(4))) float f32x4;      // MFMA accum / nt vec

__device__ __forceinline__ unsigned short f2bf(float f) {
  union { float f; unsigned int u; } a;
  a.f = f;
  unsigned int u = a.u;
  u += 0x7fffu + ((u >> 16) & 1u);   // round-to-nearest-even
  return (unsigned short)(u >> 16);
}

__device__ __forceinline__ void gload_lds16(const void* g, void* l) {
  __builtin_amdgcn_global_load_lds(
      (const __attribute__((address_space(1))) void*)g,
      (__attribute__((address_space(3))) void*)l, 16, 0, 0);
}

// ---------------- LayerNorm: fp32 -> bf16 normed rows ----------------
constexpr int D_IN = 4096;

__global__ __launch_bounds__(256) void ln_bf16_kernel(
    const float* __restrict__ x, const float* __restrict__ lnw,
    const float* __restrict__ lnb, unsigned short* __restrict__ out) {
  const int row = blockIdx.x;
  const int tid = threadIdx.x;
  const float* xr = x + (size_t)row * D_IN;

  f32x4 v[4];
  float sum = 0.f, sq = 0.f;
#pragma unroll
  for (int i = 0; i < 4; ++i) {
    v[i] = __builtin_nontemporal_load(
        reinterpret_cast<const f32x4*>(xr + i * 1024 + tid * 4));
    sum += v[i][0] + v[i][1] + v[i][2] + v[i][3];
    sq += v[i][0]*v[i][0] + v[i][1]*v[i][1] + v[i][2]*v[i][2] + v[i][3]*v[i][3];
  }
#pragma unroll
  for (int off = 32; off > 0; off >>= 1) {
    sum += __shfl_down(sum, off, 64);
    sq  += __shfl_down(sq, off, 64);
  }
  __shared__ float s_sum[4], s_sq[4];
  if ((tid & 63) == 0) { s_sum[tid >> 6] = sum; s_sq[tid >> 6] = sq; }
  __syncthreads();
  const float fs = s_sum[0] + s_sum[1] + s_sum[2] + s_sum[3];
  const float fq = s_sq[0] + s_sq[1] + s_sq[2] + s_sq[3];
  const float mean = fs * (1.f / D_IN);
  const float var = fq * (1.f / D_IN) - mean * mean;
  const float rstd = rsqrtf(var + 1e-5f);

  unsigned short* orow = out + (size_t)row * D_IN;
#pragma unroll
  for (int i = 0; i < 4; ++i) {
    const int col = i * 1024 + tid * 4;
    const f32x4 w = *reinterpret_cast<const f32x4*>(lnw + col);
    const f32x4 b = *reinterpret_cast<const f32x4*>(lnb + col);
    ushort4 o;
    o.x = f2bf((v[i][0] - mean) * rstd * w[0] + b[0]);
    o.y = f2bf((v[i][1] - mean) * rstd * w[1] + b[1]);
    o.z = f2bf((v[i][2] - mean) * rstd * w[2] + b[2]);
    o.w = f2bf((v[i][3] - mean) * rstd * w[3] + b[3]);
    *reinterpret_cast<ushort4*>(orow + col) = o;
  }
}

// ---------------- Weight cast fp32 -> bf16 ----------------
__global__ __launch_bounds__(256) void f32_to_bf16_kernel(
    const float* __restrict__ in, unsigned short* __restrict__ out) {
  const size_t i = ((size_t)blockIdx.x * 256 + threadIdx.x) * 8;
  const f32x4 a = __builtin_nontemporal_load(reinterpret_cast<const f32x4*>(in + i));
  const f32x4 b = __builtin_nontemporal_load(reinterpret_cast<const f32x4*>(in + i + 4));
  ushort4 lo, hi;
  lo.x = f2bf(a[0]); lo.y = f2bf(a[1]); lo.z = f2bf(a[2]); lo.w = f2bf(a[3]);
  hi.x = f2bf(b[0]); hi.y = f2bf(b[1]); hi.z = f2bf(b[2]); hi.w = f2bf(b[3]);
  *reinterpret_cast<ushort4*>(out + i) = lo;
  *reinterpret_cast<ushort4*>(out + i + 4) = hi;
}

// ---------------- 256x256 bf16 GEMM: A-in-LDS, B-direct-from-L2 ------
// C = A(MxK) * B(NxK)^T + bias.  512 thr = 8 waves (2M x 4N), per-wave 128x64.
// LEDGER (r12/r16 post-mortem): r12 = serial sum of LDS-read floor (361us)
// + MFMA floor (379us); r16 = at the 128^2-tile LDS roofline (723us).
// FIX: B fragments read DIRECTLY from global (L2-hot via supertile) into
// registers — vm-counted, no barrier in their path, overlapped under MFMA
// by compiler counted-waits (m97 mechanism).  LDS = A only: 2 slots x 32KB.
// LDS reads drop 192->128 KB/ktile (floor 241us).  L2-side 12.6GB ~ 20TB/s.
// Sync: X = {issue B(k,kk1); read A kk0; MFMA32(kk0); read A kk1; lgkm(0);
// bar} (stage-WAR gate).  Y = {stage A k+2 (4 units); issue B(k+1,kk0);
// MFMA32(kk1); bar}.  No manual vmcnt in steady loop: each wave's implicit
// wait-for-B before MFMA drains its older stage loads (in-order vm queue),
// so the Y barrier publishes stage(k+1) for X(k+1).  Race-audited.

#define RD(P, IMM) (*reinterpret_cast<const short8_t*>((P) + (IMM)))

#define READ_A8(S, KK)                                              \
  _Pragma("unroll") for (int m_ = 0; m_ < 8; ++m_)                  \
    af[m_] = RD((KK) ? aB1 : aB0, (S)*32768 + m_*2048);

#define LOADB(BF, KT, KK)                                           \
  _Pragma("unroll") for (int n_ = 0; n_ < 4; ++n_)                  \
    BF[n_] = *reinterpret_cast<const short8_t*>(                    \
        bG + (size_t)n_ * 16 * K + (KT)*64 + (KK)*32);

#define MFMA32(BF)                                                  \
  _Pragma("unroll") for (int m_ = 0; m_ < 8; ++m_) {                \
    _Pragma("unroll") for (int n_ = 0; n_ < 4; ++n_)                \
      acc[m_][n_] = __builtin_amdgcn_mfma_f32_16x16x32_bf16(        \
          af[m_], BF[n_], acc[m_][n_], 0, 0, 0);                    \
  }

#define STAGE_A4(S, KT)                                             \
  gload_lds16(aSrc + (size_t)(KT)*64,                 ldsAw + (S)*32768);          \
  gload_lds16(aSrc + (size_t)64*K  + (size_t)(KT)*64, ldsAw + (S)*32768 + 8192);   \
  gload_lds16(aSrc + (size_t)128*K + (size_t)(KT)*64, ldsAw + (S)*32768 + 16384);  \
  gload_lds16(aSrc + (size_t)192*K + (size_t)(KT)*64, ldsAw + (S)*32768 + 24576);

// X: issue B(k,kk1)->bfB; read A kk0; MFMA(kk0,bfA); read A kk1; WAR gate
#define XREG(S, KT)                                                 \
  LOADB(bfB, KT, 1)                                                 \
  READ_A8(S, 0)                                                     \
  __builtin_amdgcn_s_setprio(1);                                    \
  MFMA32(bfA)                                                       \
  __builtin_amdgcn_s_setprio(0);                                    \
  READ_A8(S, 1)                                                     \
  asm volatile("s_waitcnt lgkmcnt(0)" ::: "memory");                \
  __builtin_amdgcn_s_barrier();                                     \
  asm volatile("" ::: "memory");

// Y: stage A ktile KT2 into slot S; issue B(KTB,kk0)->bfA; MFMA(kk1,bfB)
#define YREG(S, KT2, KTB)                                           \
  STAGE_A4(S, KT2)                                                  \
  LOADB(bfA, KTB, 0)                                                \
  __builtin_amdgcn_s_setprio(1);                                    \
  MFMA32(bfB)                                                       \
  __builtin_amdgcn_s_setprio(0);                                    \
  __builtin_amdgcn_s_barrier();                                     \
  asm volatile("" ::: "memory");

__global__ __launch_bounds__(512, 2) void gemm_bdir(
    const unsigned short* __restrict__ A,   // M x K bf16
    const unsigned short* __restrict__ B,   // N x K bf16
    const float* __restrict__ bias,         // N fp32
    float* __restrict__ C,                  // M x N fp32
    int M, int N, int K, int NYB, int BXP) {
  extern __shared__ char smem[];
  const int tid = threadIdx.x;
  const int lane = tid & 63;
  const int wid = tid >> 6;                 // 0..7
  const int wr = wid >> 2, wc = wid & 3;    // 2M x 4N waves
  const int fr = lane & 15;
  const int q16 = (lane >> 4) * 16;

  // Super-tiled XCD mapping: window per XCD = 8(by) x BXP(bx)
  const int id = blockIdx.x;
  const int xcd = id & 7;
  const int s = id >> 3;
  const int gsz = 8 * BXP;
  const int g = s / gsz;
  const int j = s - g * gsz;
  const int by = g * 8 + (j & 7);
  const int bx = xcd * BXP + (j >> 3);
  const int m0 = by * 256, n0 = bx * 256;

  // inverse-swizzled global source for linear global_load_lds dest (A only)
  const int s_log = (tid * 16) ^ (((tid >> 3) & 7) << 4);
  const int rsw = s_log >> 7;               // 0..63 (64-row stage unit)
  const int csw = (s_log & 127) >> 1;
  const unsigned short* aSrc = A + (size_t)(m0 + rsw) * K + csw;

  // B direct: per-lane base (rows n0+wc*64+fr, col chunk (lane>>4)*8)
  const unsigned short* bG = B + (size_t)(n0 + wc * 64 + fr) * K + (q16 >> 1);

  char* const ldsAw = smem + wid * 1024;    // wave-uniform stage base

  // A fragment lane-base pointers (proven swizzle byte ^= (row&7)<<4)
  const int s7 = (fr & 7) << 4;
  const char* const aB0 = smem + (wr * 128 + fr) * 128 + (q16 ^ s7);
  const char* const aB1 = smem + (wr * 128 + fr) * 128 + ((64 + q16) ^ s7);

  f32x4 acc[8][4] = {};            // 128 -> AGPR
  short8_t af[8];                  // A frags, kk-rotated (32 VGPR)
  short8_t bfA[4], bfB[4];         // B frag sets (16+16 VGPR)

  // ---- prologue: stage A ktile0 -> slot0, ktile1 -> slot1; B(0,kk0) ----
  STAGE_A4(0, 0)
  STAGE_A4(1, 1)
  LOADB(bfA, 0, 0)
  asm volatile("s_waitcnt vmcnt(8)" ::: "memory");   // slot0 landed
  __builtin_amdgcn_s_barrier();
  asm volatile("" ::: "memory");

  const int NK = K >> 6;   // BK=64 ktiles (even, >= 4)
  for (int t = 0; t < (NK - 2) >> 1; ++t) {
    const int k0 = 2*t, k1 = 2*t + 1;
    XREG(0, k0)  YREG(0, k0 + 2, k1)       // ktile k0 (slot0); stage k0+2
    XREG(1, k1)  YREG(1, k1 + 2, k1 + 1)   // ktile k1 (slot1); stage k1+2
  }
  // ---- tail: ktiles NK-2 (slot0), NK-1 (slot1); no more staging ----
  {
    XREG(0, NK - 2)
    // Y' (no stage): load B(NK-1,kk0); finish NK-2 kk1
    LOADB(bfA, NK - 1, 0)
    __builtin_amdgcn_s_setprio(1);
    MFMA32(bfB)
    __builtin_amdgcn_s_setprio(0);
    __builtin_amdgcn_s_barrier();
    asm volatile("" ::: "memory");
    XREG(1, NK - 1)
    __builtin_amdgcn_s_setprio(1);
    MFMA32(bfB)                    // compiler waits bfB's vmcnt
    __builtin_amdgcn_s_setprio(0);
  }

  // ---- epilogue: direct nt stores (r16-proven clean write pattern) ----
  const int fq = lane >> 4;
  float bv[4];
#pragma unroll
  for (int n = 0; n < 4; ++n) bv[n] = bias[n0 + wc * 64 + n * 16 + fr];
#pragma unroll
  for (int m = 0; m < 8; ++m) {
#pragma unroll
    for (int jj = 0; jj < 4; ++jj) {
      const int row = m0 + wr * 128 + m * 16 + fq * 4 + jj;
      float* Crow = C + (size_t)row * N + n0 + wc * 64 + fr;
#pragma unroll
      for (int n = 0; n < 4; ++n)
        __builtin_nontemporal_store(acc[m][n][jj] + bv[n], Crow + n * 16);
    }
  }
}

extern "C" void kernel_launch(void* const* d_in, const int* in_sizes, int n_in,
                              void* d_out, int out_size, void* d_ws, size_t ws_size,
                              hipStream_t stream) {
  const float* x    = (const float*)d_in[0];
  const float* w    = (const float*)d_in[1];
  const float* bias = (const float*)d_in[2];
  const float* lnw  = (const float*)d_in[3];
  const float* lnb  = (const float*)d_in[4];
  float* out = (float*)d_out;

  const int DIN  = 4096;
  const int M    = in_sizes[0] / DIN;      // 8192
  const int DOUT = in_sizes[2];            // 12288

  unsigned short* normA = (unsigned short*)d_ws;                 // M x DIN bf16
  unsigned short* wB    = normA + (size_t)M * DIN;               // DOUT x DIN bf16

  ln_bf16_kernel<<<M, 256, 0, stream>>>(x, lnw, lnb, normA);
  f32_to_bf16_kernel<<<((size_t)DOUT * DIN) / (256 * 8), 256, 0, stream>>>(w, wB);

  const int nwg = (M / 256) * (DOUT / 256);   // 1536
  (void)hipFuncSetAttribute((const void*)gemm_bdir,
                            hipFuncAttributeMaxDynamicSharedMemorySize, 65536);
  gemm_bdir<<<nwg, 512, 65536, stream>>>(normA, wB, bias, out,
                                         M, DOUT, DIN, M / 256, (DOUT / 256) / 8);
}

// Round 18
// 1074.454 us; speedup vs baseline: 1.0650x; 1.0650x over previous
//
#include <hip/hip_runtime.h>
#include <hip/hip_bf16.h>
#include <stdint.h>

typedef __attribute__((ext_vector_type(8))) short short8_t;   // 8 x bf16 (4 VGPRs)
typedef __attribute__((ext_vector_type(4))) float f32x4;      // MFMA accum / nt vec

__device__ __forceinline__ unsigned short f2bf(float f) {
  union { float f; unsigned int u; } a;
  a.f = f;
  unsigned int u = a.u;
  u += 0x7fffu + ((u >> 16) & 1u);   // round-to-nearest-even
  return (unsigned short)(u >> 16);
}

__device__ __forceinline__ void gload_lds16(const void* g, void* l) {
  __builtin_amdgcn_global_load_lds(
      (const __attribute__((address_space(1))) void*)g,
      (__attribute__((address_space(3))) void*)l, 16, 0, 0);
}

// ---------------- LayerNorm: fp32 -> bf16 normed rows ----------------
constexpr int D_IN = 4096;

__global__ __launch_bounds__(256) void ln_bf16_kernel(
    const float* __restrict__ x, const float* __restrict__ lnw,
    const float* __restrict__ lnb, unsigned short* __restrict__ out) {
  const int row = blockIdx.x;
  const int tid = threadIdx.x;
  const float* xr = x + (size_t)row * D_IN;

  f32x4 v[4];
  float sum = 0.f, sq = 0.f;
#pragma unroll
  for (int i = 0; i < 4; ++i) {
    v[i] = __builtin_nontemporal_load(
        reinterpret_cast<const f32x4*>(xr + i * 1024 + tid * 4));
    sum += v[i][0] + v[i][1] + v[i][2] + v[i][3];
    sq += v[i][0]*v[i][0] + v[i][1]*v[i][1] + v[i][2]*v[i][2] + v[i][3]*v[i][3];
  }
#pragma unroll
  for (int off = 32; off > 0; off >>= 1) {
    sum += __shfl_down(sum, off, 64);
    sq  += __shfl_down(sq, off, 64);
  }
  __shared__ float s_sum[4], s_sq[4];
  if ((tid & 63) == 0) { s_sum[tid >> 6] = sum; s_sq[tid >> 6] = sq; }
  __syncthreads();
  const float fs = s_sum[0] + s_sum[1] + s_sum[2] + s_sum[3];
  const float fq = s_sq[0] + s_sq[1] + s_sq[2] + s_sq[3];
  const float mean = fs * (1.f / D_IN);
  const float var = fq * (1.f / D_IN) - mean * mean;
  const float rstd = rsqrtf(var + 1e-5f);

  unsigned short* orow = out + (size_t)row * D_IN;
#pragma unroll
  for (int i = 0; i < 4; ++i) {
    const int col = i * 1024 + tid * 4;
    const f32x4 w = *reinterpret_cast<const f32x4*>(lnw + col);
    const f32x4 b = *reinterpret_cast<const f32x4*>(lnb + col);
    ushort4 o;
    o.x = f2bf((v[i][0] - mean) * rstd * w[0] + b[0]);
    o.y = f2bf((v[i][1] - mean) * rstd * w[1] + b[1]);
    o.z = f2bf((v[i][2] - mean) * rstd * w[2] + b[2]);
    o.w = f2bf((v[i][3] - mean) * rstd * w[3] + b[3]);
    *reinterpret_cast<ushort4*>(orow + col) = o;
  }
}

// ---------------- Weight cast fp32 -> bf16 ----------------
__global__ __launch_bounds__(256) void f32_to_bf16_kernel(
    const float* __restrict__ in, unsigned short* __restrict__ out) {
  const size_t i = ((size_t)blockIdx.x * 256 + threadIdx.x) * 8;
  const f32x4 a = __builtin_nontemporal_load(reinterpret_cast<const f32x4*>(in + i));
  const f32x4 b = __builtin_nontemporal_load(reinterpret_cast<const f32x4*>(in + i + 4));
  ushort4 lo, hi;
  lo.x = f2bf(a[0]); lo.y = f2bf(a[1]); lo.z = f2bf(a[2]); lo.w = f2bf(a[3]);
  hi.x = f2bf(b[0]); hi.y = f2bf(b[1]); hi.z = f2bf(b[2]); hi.w = f2bf(b[3]);
  *reinterpret_cast<ushort4*>(out + i) = lo;
  *reinterpret_cast<ushort4*>(out + i + 4) = hi;
}

// ---------------- 256x128 bf16 GEMM: 2 blocks/CU + low LDS traffic ------
// C = A(MxK) * B(NxK)^T + bias.  512 thr = 8 waves (4M x 2N), per-wave 64x64.
// BK=64.  LDS 64 KiB exactly: A single-buffer @ 0 (32K), B dbuf @ 32K/48K.
// LEDGER: r16 proved 2 blocks/CU overlap LDS+MFMA (hit its own LDS roofline,
// 723us @ 0.047 B/FLOP); r12 had 0.023 B/FLOP but 1 block/CU (serial sum).
// This tile: 0.031 B/FLOP -> LDS floor 483us, MFMA 397us, 2 blocks/CU.
// Swizzle byte ^= ((row&7)<<4): 0 conflicts (r6-verified shape).
// Per ktile k (B slot S=k&1):
//  X: read kk0 (4A+4B) -> MFMA16 -> read kk1 (same regs, in-order WAR);
//     lgkm(0)+bar  => A(k),B(k) fully read by ALL waves -> restage safe.
//  Y: stage A(k+1) (4 units) + B(k+2)->slot S (2 units); MFMA16 (kk1,
//     operands drained at X-end); vmcnt(2)+bar => A(k+1),B(k+1) landed,
//     B(k+2) keeps 1 full region of latency cover.

#define RD(P, IMM) (*reinterpret_cast<const short8_t*>((P) + (IMM)))

#define READ8(S, KK)                                                \
  _Pragma("unroll") for (int m_ = 0; m_ < 4; ++m_)                  \
    af[m_] = RD((KK) ? aB1 : aB0, m_*2048);                         \
  _Pragma("unroll") for (int n_ = 0; n_ < 4; ++n_)                  \
    bfr[n_] = RD((KK) ? bB1 : bB0, (S)*16384 + n_*2048);

#define MFMA16                                                      \
  _Pragma("unroll") for (int m_ = 0; m_ < 4; ++m_) {                \
    _Pragma("unroll") for (int n_ = 0; n_ < 4; ++n_)                \
      acc[m_][n_] = __builtin_amdgcn_mfma_f32_16x16x32_bf16(        \
          af[m_], bfr[n_], acc[m_][n_], 0, 0, 0);                   \
  }

#define STAGE_A4(KT)                                                \
  gload_lds16(aSrc + (size_t)(KT)*64,                 ldsAw);           \
  gload_lds16(aSrc + (size_t)64*K  + (size_t)(KT)*64, ldsAw + 8192);    \
  gload_lds16(aSrc + (size_t)128*K + (size_t)(KT)*64, ldsAw + 16384);   \
  gload_lds16(aSrc + (size_t)192*K + (size_t)(KT)*64, ldsAw + 24576);
#define STAGE_B2(S, KT)                                             \
  gload_lds16(bSrc + (size_t)(KT)*64,                ldsBw + (S)*16384);        \
  gload_lds16(bSrc + (size_t)64*K + (size_t)(KT)*64, ldsBw + (S)*16384 + 8192);

// X: reads + kk0 MFMAs + kk1 reads; read-complete gate
#define XREG(S)                                                     \
  READ8(S, 0)                                                       \
  __builtin_amdgcn_s_setprio(1);                                    \
  MFMA16                                                            \
  __builtin_amdgcn_s_setprio(0);                                    \
  READ8(S, 1)                                                       \
  asm volatile("s_waitcnt lgkmcnt(0)" ::: "memory");                \
  __builtin_amdgcn_s_barrier();                                     \
  asm volatile("" ::: "memory");

// Y: restage A(k+1) + B(k+2); kk1 MFMAs (wait-free); counted-vmcnt gate
#define YREG(S, KTA, KTB)                                           \
  STAGE_A4(KTA)                                                     \
  STAGE_B2(S, KTB)                                                  \
  __builtin_amdgcn_s_setprio(1);                                    \
  MFMA16                                                            \
  __builtin_amdgcn_s_setprio(0);                                    \
  asm volatile("s_waitcnt vmcnt(2)" ::: "memory");                  \
  __builtin_amdgcn_s_barrier();                                     \
  asm volatile("" ::: "memory");

__global__ __launch_bounds__(512, 4) void gemm_ab(
    const unsigned short* __restrict__ A,   // M x K bf16
    const unsigned short* __restrict__ B,   // N x K bf16
    const float* __restrict__ bias,         // N fp32
    float* __restrict__ C,                  // M x N fp32
    int M, int N, int K, int NYB, int BXP) {
  extern __shared__ char smem[];
  const int tid = threadIdx.x;
  const int lane = tid & 63;
  const int wid = tid >> 6;                 // 0..7
  const int wr = wid >> 1, wc = wid & 1;    // 4M x 2N waves
  const int fr = lane & 15;
  const int q16 = (lane >> 4) * 16;

  // Super-tiled XCD mapping: window per XCD = 8(by) x BXP(bx)
  const int id = blockIdx.x;
  const int xcd = id & 7;
  const int s = id >> 3;
  const int gsz = 8 * BXP;
  const int g = s / gsz;
  const int j = s - g * gsz;
  const int by = g * 8 + (j & 7);
  const int bx = xcd * BXP + (j >> 3);
  const int m0 = by * 256, n0 = bx * 128;

  // inverse-swizzled global source for linear global_load_lds dest
  const int s_log = (tid * 16) ^ (((tid >> 3) & 7) << 4);
  const int rsw = s_log >> 7;               // 0..63 (64-row stage unit)
  const int csw = (s_log & 127) >> 1;
  const unsigned short* aSrc = A + (size_t)(m0 + rsw) * K + csw;
  const unsigned short* bSrc = B + (size_t)(n0 + rsw) * K + csw;

  char* const ldsAw = smem + wid * 1024;            // wave-uniform stage bases
  char* const ldsBw = smem + 32768 + wid * 1024;

  // fragment lane-base pointers (swizzle byte ^= (row&7)<<4)
  const int s7 = (fr & 7) << 4;
  const char* const aB0 = smem + (wr * 64 + fr) * 128 + (q16 ^ s7);
  const char* const aB1 = smem + (wr * 64 + fr) * 128 + ((64 + q16) ^ s7);
  const char* const bB0 = smem + 32768 + (wc * 64 + fr) * 128 + (q16 ^ s7);
  const char* const bB1 = smem + 32768 + (wc * 64 + fr) * 128 + ((64 + q16) ^ s7);

  f32x4 acc[4][4] = {};            // 64 -> AGPR
  short8_t af[4], bfr[4];          // 32 VGPR, kk-rotated

  // ---- prologue: A(0); B(0)->slot0; B(1)->slot1 ----
  STAGE_A4(0)
  STAGE_B2(0, 0)
  STAGE_B2(1, 1)
  asm volatile("s_waitcnt vmcnt(2)" ::: "memory");   // A(0),B(0) landed
  __builtin_amdgcn_s_barrier();
  asm volatile("" ::: "memory");

  const int NK = K >> 6;   // BK=64 ktiles (even, >= 4)
  for (int t = 0; t < (NK - 2) >> 1; ++t) {
    const int k0 = 2*t, k1 = 2*t + 1;
    XREG(0) YREG(0, k0 + 1, k0 + 2)    // ktile k0: stage A(k0+1), B(k0+2)
    XREG(1) YREG(1, k1 + 1, k1 + 2)    // ktile k1: stage A(k1+1), B(k1+2)
  }
  // ---- tail: ktiles NK-2 (slot0), NK-1 (slot1) ----
  {
    XREG(0)
    STAGE_A4(NK - 1)                   // only A remains to stage
    __builtin_amdgcn_s_setprio(1);
    MFMA16
    __builtin_amdgcn_s_setprio(0);
    asm volatile("s_waitcnt vmcnt(0)" ::: "memory");
    __builtin_amdgcn_s_barrier();
    asm volatile("" ::: "memory");
    READ8(1, 0)
    __builtin_amdgcn_s_setprio(1);
    MFMA16
    __builtin_amdgcn_s_setprio(0);
    READ8(1, 1)
    __builtin_amdgcn_s_setprio(1);
    MFMA16                             // compiler counted-lgkm protects
    __builtin_amdgcn_s_setprio(0);
  }

  // ---- epilogue: direct nt stores (r16-proven clean write pattern) ----
  const int fq = lane >> 4;
  float bv[4];
#pragma unroll
  for (int n = 0; n < 4; ++n) bv[n] = bias[n0 + wc * 64 + n * 16 + fr];
#pragma unroll
  for (int m = 0; m < 4; ++m) {
#pragma unroll
    for (int jj = 0; jj < 4; ++jj) {
      const int row = m0 + wr * 64 + m * 16 + fq * 4 + jj;
      float* Crow = C + (size_t)row * N + n0 + wc * 64 + fr;
#pragma unroll
      for (int n = 0; n < 4; ++n)
        __builtin_nontemporal_store(acc[m][n][jj] + bv[n], Crow + n * 16);
    }
  }
}

extern "C" void kernel_launch(void* const* d_in, const int* in_sizes, int n_in,
                              void* d_out, int out_size, void* d_ws, size_t ws_size,
                              hipStream_t stream) {
  const float* x    = (const float*)d_in[0];
  const float* w    = (const float*)d_in[1];
  const float* bias = (const float*)d_in[2];
  const float* lnw  = (const float*)d_in[3];
  const float* lnb  = (const float*)d_in[4];
  float* out = (float*)d_out;

  const int DIN  = 4096;
  const int M    = in_sizes[0] / DIN;      // 8192
  const int DOUT = in_sizes[2];            // 12288

  unsigned short* normA = (unsigned short*)d_ws;                 // M x DIN bf16
  unsigned short* wB    = normA + (size_t)M * DIN;               // DOUT x DIN bf16

  ln_bf16_kernel<<<M, 256, 0, stream>>>(x, lnw, lnb, normA);
  f32_to_bf16_kernel<<<((size_t)DOUT * DIN) / (256 * 8), 256, 0, stream>>>(w, wB);

  const int nwg = (M / 256) * (DOUT / 128);   // 32 x 96 = 3072
  (void)hipFuncSetAttribute((const void*)gemm_ab,
                            hipFuncAttributeMaxDynamicSharedMemorySize, 65536);
  gemm_ab<<<nwg, 512, 65536, stream>>>(normA, wB, bias, out,
                                       M, DOUT, DIN, M / 256, (DOUT / 128) / 8);
}

// Round 19
// 730.287 us; speedup vs baseline: 1.5668x; 1.4713x over previous
//
#include <hip/hip_runtime.h>
#include <hip/hip_bf16.h>
#include <stdint.h>

typedef __attribute__((ext_vector_type(8))) short short8_t;   // 8 x bf16 (4 VGPRs)
typedef __attribute__((ext_vector_type(4))) float f32x4;      // MFMA accum / nt vec

__device__ __forceinline__ unsigned short f2bf(float f) {
  union { float f; unsigned int u; } a;
  a.f = f;
  unsigned int u = a.u;
  u += 0x7fffu + ((u >> 16) & 1u);   // round-to-nearest-even
  return (unsigned short)(u >> 16);
}

__device__ __forceinline__ void gload_lds16(const void* g, void* l) {
  __builtin_amdgcn_global_load_lds(
      (const __attribute__((address_space(1))) void*)g,
      (__attribute__((address_space(3))) void*)l, 16, 0, 0);
}

// ---------------- LayerNorm: fp32 -> bf16 normed rows ----------------
constexpr int D_IN = 4096;

__global__ __launch_bounds__(256) void ln_bf16_kernel(
    const float* __restrict__ x, const float* __restrict__ lnw,
    const float* __restrict__ lnb, unsigned short* __restrict__ out) {
  const int row = blockIdx.x;
  const int tid = threadIdx.x;
  const float* xr = x + (size_t)row * D_IN;

  f32x4 v[4];
  float sum = 0.f, sq = 0.f;
#pragma unroll
  for (int i = 0; i < 4; ++i) {
    v[i] = __builtin_nontemporal_load(
        reinterpret_cast<const f32x4*>(xr + i * 1024 + tid * 4));
    sum += v[i][0] + v[i][1] + v[i][2] + v[i][3];
    sq += v[i][0]*v[i][0] + v[i][1]*v[i][1] + v[i][2]*v[i][2] + v[i][3]*v[i][3];
  }
#pragma unroll
  for (int off = 32; off > 0; off >>= 1) {
    sum += __shfl_down(sum, off, 64);
    sq  += __shfl_down(sq, off, 64);
  }
  __shared__ float s_sum[4], s_sq[4];
  if ((tid & 63) == 0) { s_sum[tid >> 6] = sum; s_sq[tid >> 6] = sq; }
  __syncthreads();
  const float fs = s_sum[0] + s_sum[1] + s_sum[2] + s_sum[3];
  const float fq = s_sq[0] + s_sq[1] + s_sq[2] + s_sq[3];
  const float mean = fs * (1.f / D_IN);
  const float var = fq * (1.f / D_IN) - mean * mean;
  const float rstd = rsqrtf(var + 1e-5f);

  unsigned short* orow = out + (size_t)row * D_IN;
#pragma unroll
  for (int i = 0; i < 4; ++i) {
    const int col = i * 1024 + tid * 4;
    const f32x4 w = *reinterpret_cast<const f32x4*>(lnw + col);
    const f32x4 b = *reinterpret_cast<const f32x4*>(lnb + col);
    ushort4 o;
    o.x = f2bf((v[i][0] - mean) * rstd * w[0] + b[0]);
    o.y = f2bf((v[i][1] - mean) * rstd * w[1] + b[1]);
    o.z = f2bf((v[i][2] - mean) * rstd * w[2] + b[2]);
    o.w = f2bf((v[i][3] - mean) * rstd * w[3] + b[3]);
    *reinterpret_cast<ushort4*>(orow + col) = o;
  }
}

// ---------------- Weight cast fp32 -> bf16 ----------------
__global__ __launch_bounds__(256) void f32_to_bf16_kernel(
    const float* __restrict__ in, unsigned short* __restrict__ out) {
  const size_t i = ((size_t)blockIdx.x * 256 + threadIdx.x) * 8;
  const f32x4 a = __builtin_nontemporal_load(reinterpret_cast<const f32x4*>(in + i));
  const f32x4 b = __builtin_nontemporal_load(reinterpret_cast<const f32x4*>(in + i + 4));
  ushort4 lo, hi;
  lo.x = f2bf(a[0]); lo.y = f2bf(a[1]); lo.z = f2bf(a[2]); lo.w = f2bf(a[3]);
  hi.x = f2bf(b[0]); hi.y = f2bf(b[1]); hi.z = f2bf(b[2]); hi.w = f2bf(b[3]);
  *reinterpret_cast<ushort4*>(out + i) = lo;
  *reinterpret_cast<ushort4*>(out + i + 4) = hi;
}

// ---------------- 256x256 bf16 GEMM: X/Y regions + super-tiled mapping ------
// REVERT TO BEST (r12, 729.5 us total).  The r13-r18 exploration proved:
//  - 2 blocks/CU overlap works (r16) but only reachable at 128^2 tile, which
//    sits on its own LDS-traffic roofline (0.046 B/FLOP -> 723 us floor).
//  - Bridging tiles (256x128 @ 2 blocks/CU) are register-infeasible:
//    acc 64 + frags + addressing > 128 unified cap -> spill (r13, r18).
//  - B-direct-from-L2 dies on per-lane 8KB address stride (r17).
//  - Intra-block pipelining (r9/r11/r14/r15) is null or worse.
// r12 = serial sum of LDS floor (361us) + MFMA floor (379us) at 1 block/CU:
// the empirical basin floor of this structure family (~1.13 PF GEMM).
//
// C = A(MxK) * B(NxK)^T + bias.  8 waves (2M x 4N), BK=64, per-ktile loop.
// LDS: A slot0/1 @ 0/32K, B slot0/1 @ 64K/96K.  16x16x32 MFMA.
// Swizzle byte ^= ((row&7)<<4): verified 0 conflicts.
// Schedule: X = reads + first-half MFMAs + lgkm(0)+bar (stage-WAR gate);
//           Y = stage refill + second-half MFMAs + vmcnt(8)+bar (counted).
// Mapping: per XCD the concurrent window is an 8(by) x BXP(bx) super-tile
// -> per round A = 8 panels (16MB, same on all XCDs, L3-persistent) +
// B = BXP panels/XCD (L2-resident).  FETCH 1.62GB -> 0.72GB measured.

#define RDA(S, KK, ROW) \
  (*reinterpret_cast<const short8_t*>(((KK) ? aB1 : aB0) + (S)*32768 + (ROW)*128))
#define RDB(S, KK, ROW) \
  (*reinterpret_cast<const short8_t*>(((KK) ? bB1 : bB0) + (S)*32768 + (ROW)*128))

#define READ_A(S, MH)                                          \
  _Pragma("unroll") for (int m_ = 0; m_ < 4; ++m_) {           \
    af[m_][0] = RDA(S, 0, (MH)*64 + m_*16);                    \
    af[m_][1] = RDA(S, 1, (MH)*64 + m_*16);                    \
  }

#define READ_B(S, NH)                                          \
  _Pragma("unroll") for (int n_ = 0; n_ < 2; ++n_) {           \
    bfr[(NH)*2+n_][0] = RDB(S, 0, ((NH)*2+n_)*16);             \
    bfr[(NH)*2+n_][1] = RDB(S, 1, ((NH)*2+n_)*16);             \
  }

#define MFMA_Q(MH, NH)                                                         \
  _Pragma("unroll") for (int kk_ = 0; kk_ < 2; ++kk_) {                        \
    _Pragma("unroll") for (int m_ = 0; m_ < 4; ++m_) {                         \
      _Pragma("unroll") for (int n_ = 0; n_ < 2; ++n_)                         \
        acc[(MH)*4+m_][(NH)*2+n_] = __builtin_amdgcn_mfma_f32_16x16x32_bf16(   \
            af[m_][kk_], bfr[(NH)*2+n_][kk_], acc[(MH)*4+m_][(NH)*2+n_], 0, 0, 0); \
    }                                                                          \
  }

#define STAGE_A(S, U, KT) \
  gload_lds16(aSrc + (size_t)((U)*64) * K + (size_t)(KT)*64, ldsAw + (S)*32768 + (U)*8192)
#define STAGE_B(S, U, KT) \
  gload_lds16(bSrc + (size_t)((U)*64) * K + (size_t)(KT)*64, ldsBw + (S)*32768 + (U)*8192)
#define STAGE_ALL(S, KT)                                       \
  STAGE_A(S,0,KT); STAGE_A(S,1,KT); STAGE_A(S,2,KT); STAGE_A(S,3,KT); \
  STAGE_B(S,0,KT); STAGE_B(S,1,KT); STAGE_B(S,2,KT); STAGE_B(S,3,KT);

// X region: reads + first-half MFMAs, then stage-WAR gate
#define XREG(S)                                                \
  READ_A(S, 0) READ_B(S, 0)                                    \
  __builtin_amdgcn_s_setprio(1);                               \
  MFMA_Q(0,0)                                                  \
  READ_B(S, 1)                                                 \
  MFMA_Q(0,1)                                                  \
  READ_A(S, 1)                                                 \
  __builtin_amdgcn_s_setprio(0);                               \
  asm volatile("s_waitcnt lgkmcnt(0)" ::: "memory");           \
  __builtin_amdgcn_s_barrier();                                \
  asm volatile("" ::: "memory");

// Y region: stage refill + second-half MFMAs, counted-vmcnt gate
#define YREG(S, KT)                                            \
  STAGE_ALL(S, KT)                                             \
  __builtin_amdgcn_s_setprio(1);                               \
  MFMA_Q(1,0)                                                  \
  MFMA_Q(1,1)                                                  \
  __builtin_amdgcn_s_setprio(0);                               \
  asm volatile("s_waitcnt vmcnt(8)" ::: "memory");             \
  __builtin_amdgcn_s_barrier();                                \
  asm volatile("" ::: "memory");

__global__ __launch_bounds__(512, 2) void gemm_xy(
    const unsigned short* __restrict__ A,   // M x K bf16
    const unsigned short* __restrict__ B,   // N x K bf16
    const float* __restrict__ bias,         // N fp32
    float* __restrict__ C,                  // M x N fp32
    int M, int N, int K, int NYB, int BXP) {
  extern __shared__ char smem[];
  const int tid = threadIdx.x;
  const int lane = tid & 63;
  const int wid = tid >> 6;
  const int wr = wid >> 2, wc = wid & 3;
  const int fr = lane & 15;
  const int q16 = (lane >> 4) * 16;
  const int wr128 = wr * 128;
  const int wc64 = wc * 64;

  // Super-tiled XCD mapping: concurrent window per XCD = 8(by) x BXP(bx)
  const int id = blockIdx.x;
  const int xcd = id & 7;
  const int s = id >> 3;                 // 0 .. NYB*BXP-1
  const int gsz = 8 * BXP;               // blocks per by-group per XCD
  const int g = s / gsz;
  const int j = s - g * gsz;
  const int by = g * 8 + (j & 7);
  const int bx = xcd * BXP + (j >> 3);
  const int m0 = by * 256, n0 = bx * 256;

  // inverse-swizzled global source for linear global_load_lds dest
  const int s_log = (tid * 16) ^ (((tid >> 3) & 7) << 4);
  const int rsw = s_log >> 7;
  const int csw = (s_log & 127) >> 1;
  const unsigned short* aSrc = A + (size_t)(m0 + rsw) * K + csw;
  const unsigned short* bSrc = B + (size_t)(n0 + rsw) * K + csw;

  char* const ldsAw = smem + wid * 1024;           // wave-uniform stage bases
  char* const ldsBw = smem + 65536 + wid * 1024;

  // 4 lane-base pointers: all fragment reads are base + compile-time offset
  const int s7 = (fr & 7) << 4;
  const char* const aB0 = smem + (wr128 + fr) * 128 + (q16 ^ s7);
  const char* const aB1 = smem + (wr128 + fr) * 128 + ((64 + q16) ^ s7);
  const char* const bB0 = smem + 65536 + (wc64 + fr) * 128 + (q16 ^ s7);
  const char* const bB1 = smem + 65536 + (wc64 + fr) * 128 + ((64 + q16) ^ s7);

  f32x4 acc[8][4] = {};
  short8_t af[4][2], bfr[4][2];

  // ---- prologue: ktile0 -> slot0, ktile1 -> slot1 (8 units each) ----
  STAGE_ALL(0, 0)
  STAGE_ALL(1, 1)
  asm volatile("s_waitcnt vmcnt(8)" ::: "memory");   // ktile0 landed
  __builtin_amdgcn_s_barrier();
  asm volatile("" ::: "memory");

  const int NK = K >> 6;   // ktiles of BK=64 (even; >= 4)
  for (int t = 0; t < (NK - 2) >> 1; ++t) {
    const int k2 = 2*t + 2, k3 = 2*t + 3;
    XREG(0) YREG(0, k2)      // ktile 2t   (slot0), refill slot0 <- ktile 2t+2
    XREG(1) YREG(1, k3)      // ktile 2t+1 (slot1), refill slot1 <- ktile 2t+3
  }
  // ---- tail: ktiles NK-2 (slot0), NK-1 (slot1); no more staging ----
  {
    READ_A(0, 0) READ_B(0, 0)
    __builtin_amdgcn_s_setprio(1);
    MFMA_Q(0,0)
    READ_B(0, 1)
    MFMA_Q(0,1)
    READ_A(0, 1)
    MFMA_Q(1,0)
    MFMA_Q(1,1)
    __builtin_amdgcn_s_setprio(0);
    asm volatile("s_waitcnt lgkmcnt(0)\n\ts_waitcnt vmcnt(0)" ::: "memory");
    __builtin_amdgcn_s_barrier();    // ktile NK-1 landed & published
    asm volatile("" ::: "memory");
    READ_A(1, 0) READ_B(1, 0)
    __builtin_amdgcn_s_setprio(1);
    MFMA_Q(0,0)
    READ_B(1, 1)
    MFMA_Q(0,1)
    READ_A(1, 1)
    MFMA_Q(1,0)
    MFMA_Q(1,1)
    __builtin_amdgcn_s_setprio(0);
  }

  // ---- epilogue: LDS-transpose -> fully-contiguous 1KB nt stores ----
  __syncthreads();   // all waves' K-loop LDS reads done before overwrite
  float* const buf0 = (float*)smem;
  float* const buf1 = (float*)smem + 64 * 260;
  const int cr = (lane >> 4) * 4;
  float bv[4];
#pragma unroll
  for (int ni = 0; ni < 4; ++ni) bv[ni] = bias[n0 + wc64 + ni * 16 + fr];

#pragma unroll
  for (int half = 0; half < 2; ++half) {
    float* const wbuf = (wr == 0) ? buf0 : buf1;
#pragma unroll
    for (int mi4 = 0; mi4 < 4; ++mi4) {
      const int mi = half * 4 + mi4;
#pragma unroll
      for (int j2 = 0; j2 < 4; ++j2) {
        const int lr = mi4 * 16 + cr + j2;   // local row 0..63
#pragma unroll
        for (int ni = 0; ni < 4; ++ni)
          wbuf[lr * 260 + wc64 + ni * 16 + fr] = acc[mi][ni][j2] + bv[ni];
      }
    }
    __syncthreads();
#pragma unroll
    for (int i = 0; i < 16; ++i) {
      const int idx = wid * 16 + i;   // 0..127, wave-uniform buffer choice
      const float* src = (idx < 64 ? buf0 + idx * 260 : buf1 + (idx - 64) * 260) + lane * 4;
      const int grow = m0 + (idx < 64 ? half * 64 + idx : 128 + half * 64 + (idx - 64));
      const f32x4 vv = *reinterpret_cast<const f32x4*>(src);
      __builtin_nontemporal_store(
          vv, reinterpret_cast<f32x4*>(C + (size_t)grow * N + n0) + lane);
    }
    __syncthreads();
  }
}

extern "C" void kernel_launch(void* const* d_in, const int* in_sizes, int n_in,
                              void* d_out, int out_size, void* d_ws, size_t ws_size,
                              hipStream_t stream) {
  const float* x    = (const float*)d_in[0];
  const float* w    = (const float*)d_in[1];
  const float* bias = (const float*)d_in[2];
  const float* lnw  = (const float*)d_in[3];
  const float* lnb  = (const float*)d_in[4];
  float* out = (float*)d_out;

  const int DIN  = 4096;
  const int M    = in_sizes[0] / DIN;      // 8192
  const int DOUT = in_sizes[2];            // 12288

  unsigned short* normA = (unsigned short*)d_ws;                 // M x DIN bf16
  unsigned short* wB    = normA + (size_t)M * DIN;               // DOUT x DIN bf16

  ln_bf16_kernel<<<M, 256, 0, stream>>>(x, lnw, lnb, normA);
  f32_to_bf16_kernel<<<((size_t)DOUT * DIN) / (256 * 8), 256, 0, stream>>>(w, wB);

  const int nwg = (M / 256) * (DOUT / 256);   // 1536
  const int smem_bytes = 2 * 64 * 260 * 4 > 131072 ? 2 * 64 * 260 * 4 : 131072; // 133120
  (void)hipFuncSetAttribute((const void*)gemm_xy,
                            hipFuncAttributeMaxDynamicSharedMemorySize, 163840);
  gemm_xy<<<nwg, 512, smem_bytes, stream>>>(normA, wB, bias, out,
                                            M, DOUT, DIN, M / 256, (DOUT / 256) / 8);
}